// Round 5
// baseline (1540.995 us; speedup 1.0000x reference)
//
#include <hip/hip_runtime.h>
#include <math.h>

#define NS   512   // states
#define NO   1024  // observations
#define NB   64    // batch
#define TMAX 512

#define QREG 48    // uint4 chunks (8 fp16 k each) pinned in VGPRs: k 0..383
#define QLDS 16    // chunks in LDS:                                k 384..511

typedef _Float16 h2v __attribute__((ext_vector_type(2)));

__device__ inline float wave_red_sum(float x) {
#pragma unroll
  for (int o = 32; o; o >>= 1) x += __shfl_xor(x, o, 64);
  return x;
}
__device__ inline float wave_red_max(float x) {
#pragma unroll
  for (int o = 32; o; o >>= 1) x = fmaxf(x, __shfl_xor(x, o, 64));
  return x;
}

__device__ inline float dot2u(unsigned int a, unsigned int b, float c) {
#if __has_builtin(__builtin_amdgcn_fdot2)
  return __builtin_amdgcn_fdot2(__builtin_bit_cast(h2v, a),
                                __builtin_bit_cast(h2v, b), c, false);
#else
  h2v av = __builtin_bit_cast(h2v, a), bv = __builtin_bit_cast(h2v, b);
  return c + (float)av.x * (float)bv.x + (float)av.y * (float)bv.y;
#endif
}

// P1: pi softmax -> pi_sm[512]
__global__ void k_pi(const float* __restrict__ pi, float* __restrict__ pi_sm) {
  __shared__ float red[8];
  int tid = threadIdx.x;
  float v = pi[tid];
  float m = wave_red_max(v);
  if ((tid & 63) == 0) red[tid >> 6] = m;
  __syncthreads();
  m = fmaxf(fmaxf(fmaxf(red[0], red[1]), fmaxf(red[2], red[3])),
            fmaxf(fmaxf(red[4], red[5]), fmaxf(red[6], red[7])));
  float e = __expf(v - m);
  float s = wave_red_sum(e);
  __syncthreads();
  if ((tid & 63) == 0) red[tid >> 6] = s;
  __syncthreads();
  s = red[0] + red[1] + red[2] + red[3] + red[4] + red[5] + red[6] + red[7];
  pi_sm[tid] = e / s;
}

// P2: column logsumexp of A (axis 0). One block (256 thr) per column. grid 512.
__global__ void k_colLse(const float* __restrict__ A, float* __restrict__ lseA) {
  __shared__ float redm[4];
  __shared__ float reds[4];
  int k = blockIdx.x, tid = threadIdx.x;
  float a0 = A[tid * NS + k], a1 = A[(tid + 256) * NS + k];
  float m = wave_red_max(fmaxf(a0, a1));
  if ((tid & 63) == 0) redm[tid >> 6] = m;
  __syncthreads();
  m = fmaxf(fmaxf(redm[0], redm[1]), fmaxf(redm[2], redm[3]));
  float s = __expf(a0 - m) + __expf(a1 - m);
  s = wave_red_sum(s);
  if ((tid & 63) == 0) reds[tid >> 6] = s;
  __syncthreads();
  s = reds[0] + reds[1] + reds[2] + reds[3];
  if (tid == 0) lseA[k] = m + __logf(s);
}

// P3: row logsumexp of E (axis 1). One block per row. grid 512 x 256.
__global__ void k_rowLseE(const float* __restrict__ E, float* __restrict__ lseE) {
  __shared__ float red[4];
  int i = blockIdx.x, tid = threadIdx.x;
  const float* row = E + i * NO;
  float a0 = row[tid], a1 = row[tid + 256], a2 = row[tid + 512], a3 = row[tid + 768];
  float m = fmaxf(fmaxf(a0, a1), fmaxf(a2, a3));
  m = wave_red_max(m);
  if ((tid & 63) == 0) red[tid >> 6] = m;
  __syncthreads();
  m = fmaxf(fmaxf(red[0], red[1]), fmaxf(red[2], red[3]));
  float s = __expf(a0 - m) + __expf(a1 - m) + __expf(a2 - m) + __expf(a3 - m);
  s = wave_red_sum(s);
  __syncthreads();
  if ((tid & 63) == 0) red[tid >> 6] = s;
  __syncthreads();
  s = red[0] + red[1] + red[2] + red[3];
  if (tid == 0) lseE[i] = m + __logf(s);
}

// P4: pack A_exp = exp(A - lseA[col]) fp16, chunk-major: uint4 chunk
// Aall[q*512 + i] = row i, k = 8q..8q+7. grid 256 x 512 (u32 granularity).
__global__ void k_pack(const float* __restrict__ A, const float* __restrict__ lseA,
                       unsigned int* __restrict__ W) {
  int u = blockIdx.x * 512 + threadIdx.x;   // [0, 64*512*4)
  int q = u >> 11;
  int r = u & 2047;
  int i = r >> 2;
  int h = r & 3;
  int k0 = q * 8 + h * 2;
  float e0 = __expf(A[i * NS + k0]     - lseA[k0]);
  float e1 = __expf(A[i * NS + k0 + 1] - lseA[k0 + 1]);
  h2v p;
  p.x = (_Float16)e0;
  p.y = (_Float16)e1;
  W[u] = __builtin_bit_cast(unsigned int, p);
}

// P5: transposed exp'd emissions: Et[o][i] = fp16(exp(E[i][o] - lseE[i])).
// grid 1024 x 512. Makes the per-step emission read fully coalesced.
__global__ void k_Et(const float* __restrict__ E, const float* __restrict__ lseE,
                     _Float16* __restrict__ Et) {
  int o = blockIdx.x, i = threadIdx.x;
  Et[o * NS + i] = (_Float16)__expf(E[i * NO + o] - lseE[i]);
}

// Main forward: one block per batch, thread tid = output state i.
// A row i fully on-CU: 384 k pinned in VGPRs, 128 k in LDS. Zero per-step
// global A traffic. amdgpu_waves_per_eu(2,2) unlocks the 256-reg budget
// (LDS already caps us at 1 block/CU = 2 waves/SIMD, so nothing is lost).
__global__ __attribute__((amdgpu_flat_work_group_size(512, 512),
                          amdgpu_waves_per_eu(2, 2))) void k_fwd(
    const _Float16* __restrict__ Et, const int* __restrict__ x,
    const int* __restrict__ Tlen, const float* __restrict__ pi_sm,
    const uint4* __restrict__ Aall, float* __restrict__ out) {
  __shared__ uint4 Alds[QLDS * 512];   // 131072 B, conflict-free
  __shared__ uint4 vbuf[2][NS / 8];    // 2 KB
  __shared__ int xrow[TMAX];           // 2 KB
  __shared__ float red[8];
  int b = blockIdx.x, tid = threadIdx.x;

  // Register-resident A (coalesced uint4 loads) + opaque asm pin so the
  // compiler can neither sink nor rematerialize these loads into the t-loop.
  uint4 areg[QREG];
#pragma unroll
  for (int q = 0; q < QREG; q++) areg[q] = Aall[q * 512 + tid];
#pragma unroll
  for (int q = 0; q < QREG; q++)
    asm volatile("" : "+v"(areg[q].x), "+v"(areg[q].y),
                      "+v"(areg[q].z), "+v"(areg[q].w));
#pragma unroll
  for (int q = 0; q < QLDS; q++) Alds[q * 512 + tid] = Aall[(QREG + q) * 512 + tid];

  for (int t = tid; t < TMAX; t += 512) xrow[t] = x[b * TMAX + t];

  float pi_i = pi_sm[tid];
  const _Float16* Etc = Et + tid;
  int Tb = Tlen[b];
  float c = 0.f;
  int cur = 0;
  __syncthreads();

  for (int t = 0; t < Tb; t++) {
    int xt = xrow[t];
    _Float16 emh = Etc[xt * NS];     // coalesced; hidden behind the dot phase
    float acc;
    if (t == 0) {
      acc = pi_i;
    } else {
      const uint4* vp = vbuf[cur];
      float a0 = 0.f, a1 = 0.f, a2 = 0.f, a3 = 0.f;
#pragma unroll
      for (int q = 0; q < QREG; q += 4) {
        uint4 v0 = vp[q], v1 = vp[q + 1], v2 = vp[q + 2], v3 = vp[q + 3];
        a0 = dot2u(areg[q].x, v0.x, a0); a0 = dot2u(areg[q].y, v0.y, a0);
        a0 = dot2u(areg[q].z, v0.z, a0); a0 = dot2u(areg[q].w, v0.w, a0);
        a1 = dot2u(areg[q+1].x, v1.x, a1); a1 = dot2u(areg[q+1].y, v1.y, a1);
        a1 = dot2u(areg[q+1].z, v1.z, a1); a1 = dot2u(areg[q+1].w, v1.w, a1);
        a2 = dot2u(areg[q+2].x, v2.x, a2); a2 = dot2u(areg[q+2].y, v2.y, a2);
        a2 = dot2u(areg[q+2].z, v2.z, a2); a2 = dot2u(areg[q+2].w, v2.w, a2);
        a3 = dot2u(areg[q+3].x, v3.x, a3); a3 = dot2u(areg[q+3].y, v3.y, a3);
        a3 = dot2u(areg[q+3].z, v3.z, a3); a3 = dot2u(areg[q+3].w, v3.w, a3);
      }
#pragma unroll
      for (int q = 0; q < QLDS; q += 2) {
        uint4 b0 = Alds[q * 512 + tid], b1 = Alds[(q + 1) * 512 + tid];
        uint4 v0 = vp[QREG + q], v1 = vp[QREG + q + 1];
        a0 = dot2u(b0.x, v0.x, a0); a0 = dot2u(b0.y, v0.y, a0);
        a0 = dot2u(b0.z, v0.z, a0); a0 = dot2u(b0.w, v0.w, a0);
        a1 = dot2u(b1.x, v1.x, a1); a1 = dot2u(b1.y, v1.y, a1);
        a1 = dot2u(b1.z, v1.z, a1); a1 = dot2u(b1.w, v1.w, a1);
      }
      acc = (a0 + a1) + (a2 + a3);
    }
    float nv = acc * (float)emh;
    float s = wave_red_sum(nv);
    if ((tid & 63) == 0) red[tid >> 6] = s;
    __syncthreads();
    s = red[0] + red[1] + red[2] + red[3] + red[4] + red[5] + red[6] + red[7];
    c += __logf(s);
    float rs = __builtin_amdgcn_rcpf(s);
    int nxt = cur ^ 1;
    ((_Float16*)vbuf[nxt])[tid] = (_Float16)(nv * rs);
    __syncthreads();
    cur = nxt;
  }
  if (tid == 0) out[b] = c;
}

extern "C" void kernel_launch(void* const* d_in, const int* in_sizes, int n_in,
                              void* d_out, int out_size, void* d_ws, size_t ws_size,
                              hipStream_t stream) {
  const float* pi = (const float*)d_in[0];
  const float* A  = (const float*)d_in[1];
  const float* E  = (const float*)d_in[2];
  const int*   x  = (const int*)d_in[3];
  const int*   T  = (const int*)d_in[4];
  float* out = (float*)d_out;

  char* ws = (char*)d_ws;
  float*        pi_sm = (float*)(ws + 0);
  float*        lseA  = (float*)(ws + 2048);
  float*        lseE  = (float*)(ws + 4096);
  unsigned int* Apk   = (unsigned int*)(ws + 6144);            // 512 KB
  _Float16*     Et    = (_Float16*)(ws + 6144 + 524288);       // 1 MB

  hipLaunchKernelGGL(k_pi,      dim3(1),    dim3(512), 0, stream, pi, pi_sm);
  hipLaunchKernelGGL(k_colLse,  dim3(512),  dim3(256), 0, stream, A, lseA);
  hipLaunchKernelGGL(k_rowLseE, dim3(512),  dim3(256), 0, stream, E, lseE);
  hipLaunchKernelGGL(k_pack,    dim3(256),  dim3(512), 0, stream, A, lseA, Apk);
  hipLaunchKernelGGL(k_Et,      dim3(1024), dim3(512), 0, stream, E, lseE, Et);
  hipLaunchKernelGGL(k_fwd,     dim3(64),   dim3(512), 0, stream,
                     Et, x, T, pi_sm, (const uint4*)Apk, out);
}

// Round 6
// 1443.138 us; speedup vs baseline: 1.0678x; 1.0678x over previous
//
#include <hip/hip_runtime.h>
#include <math.h>

#define NS   512   // states
#define NO   1024  // observations
#define NB   64    // batch
#define TMAX 512

// Per-thread k-coverage: 256 values = 32 uint4 chunks (8 fp16 each).
#define QREG 17    // chunks in VGPRs (68 regs) : c 0..16
#define QLDS 9     // chunks in LDS (144 KB)    : c 17..25
#define QSTR 6     // chunks streamed from L2   : c 26..31

typedef _Float16 h2v __attribute__((ext_vector_type(2)));

__device__ inline float wave_red_sum(float x) {
#pragma unroll
  for (int o = 32; o; o >>= 1) x += __shfl_xor(x, o, 64);
  return x;
}
__device__ inline float wave_red_max(float x) {
#pragma unroll
  for (int o = 32; o; o >>= 1) x = fmaxf(x, __shfl_xor(x, o, 64));
  return x;
}

__device__ inline float dot2u(unsigned int a, unsigned int b, float c) {
#if __has_builtin(__builtin_amdgcn_fdot2)
  return __builtin_amdgcn_fdot2(__builtin_bit_cast(h2v, a),
                                __builtin_bit_cast(h2v, b), c, false);
#else
  h2v av = __builtin_bit_cast(h2v, a), bv = __builtin_bit_cast(h2v, b);
  return c + (float)av.x * (float)bv.x + (float)av.y * (float)bv.y;
#endif
}

// P1: pi softmax -> pi_sm[512]
__global__ void k_pi(const float* __restrict__ pi, float* __restrict__ pi_sm) {
  __shared__ float red[8];
  int tid = threadIdx.x;
  float v = pi[tid];
  float m = wave_red_max(v);
  if ((tid & 63) == 0) red[tid >> 6] = m;
  __syncthreads();
  m = fmaxf(fmaxf(fmaxf(red[0], red[1]), fmaxf(red[2], red[3])),
            fmaxf(fmaxf(red[4], red[5]), fmaxf(red[6], red[7])));
  float e = __expf(v - m);
  float s = wave_red_sum(e);
  __syncthreads();
  if ((tid & 63) == 0) red[tid >> 6] = s;
  __syncthreads();
  s = red[0] + red[1] + red[2] + red[3] + red[4] + red[5] + red[6] + red[7];
  pi_sm[tid] = e / s;
}

// P2: column logsumexp of A (axis 0). One block (256 thr) per column. grid 512.
__global__ void k_colLse(const float* __restrict__ A, float* __restrict__ lseA) {
  __shared__ float redm[4];
  __shared__ float reds[4];
  int k = blockIdx.x, tid = threadIdx.x;
  float a0 = A[tid * NS + k], a1 = A[(tid + 256) * NS + k];
  float m = wave_red_max(fmaxf(a0, a1));
  if ((tid & 63) == 0) redm[tid >> 6] = m;
  __syncthreads();
  m = fmaxf(fmaxf(redm[0], redm[1]), fmaxf(redm[2], redm[3]));
  float s = __expf(a0 - m) + __expf(a1 - m);
  s = wave_red_sum(s);
  if ((tid & 63) == 0) reds[tid >> 6] = s;
  __syncthreads();
  s = reds[0] + reds[1] + reds[2] + reds[3];
  if (tid == 0) lseA[k] = m + __logf(s);
}

// P3: row logsumexp of E (axis 1). One block per row. grid 512 x 256.
__global__ void k_rowLseE(const float* __restrict__ E, float* __restrict__ lseE) {
  __shared__ float red[4];
  int i = blockIdx.x, tid = threadIdx.x;
  const float* row = E + i * NO;
  float a0 = row[tid], a1 = row[tid + 256], a2 = row[tid + 512], a3 = row[tid + 768];
  float m = fmaxf(fmaxf(a0, a1), fmaxf(a2, a3));
  m = wave_red_max(m);
  if ((tid & 63) == 0) red[tid >> 6] = m;
  __syncthreads();
  m = fmaxf(fmaxf(red[0], red[1]), fmaxf(red[2], red[3]));
  float s = __expf(a0 - m) + __expf(a1 - m) + __expf(a2 - m) + __expf(a3 - m);
  s = wave_red_sum(s);
  __syncthreads();
  if ((tid & 63) == 0) red[tid >> 6] = s;
  __syncthreads();
  s = red[0] + red[1] + red[2] + red[3];
  if (tid == 0) lseE[i] = m + __logf(s);
}

// P4: pack A_exp = exp(A - lseA[col]) fp16, chunk-major for the 1024-thread
// layout: thread th owns state i=th>>1, half h=th&1; chunk c holds
// k = h*256 + c*8 .. +7. uint4 index = c*1024 + th. Word granularity here:
// word u -> c=u>>12, th=(u&4095)>>2, w=u&3, pair k0 = h*256 + c*8 + 2w.
__global__ void k_pack(const float* __restrict__ A, const float* __restrict__ lseA,
                       unsigned int* __restrict__ W) {
  int u = blockIdx.x * 512 + threadIdx.x;   // [0, 131072)
  int c = u >> 12;
  int r = u & 4095;
  int th = r >> 2;
  int w = r & 3;
  int i = th >> 1;
  int h = th & 1;
  int k0 = h * 256 + c * 8 + w * 2;
  float e0 = __expf(A[i * NS + k0]     - lseA[k0]);
  float e1 = __expf(A[i * NS + k0 + 1] - lseA[k0 + 1]);
  h2v p;
  p.x = (_Float16)e0;
  p.y = (_Float16)e1;
  W[u] = __builtin_bit_cast(unsigned int, p);
}

// P5: transposed exp'd emissions: Et[o][i] = fp16(exp(E[i][o] - lseE[i])).
__global__ void k_Et(const float* __restrict__ E, const float* __restrict__ lseE,
                     _Float16* __restrict__ Et) {
  int o = blockIdx.x, i = threadIdx.x;
  Et[o * NS + i] = (_Float16)__expf(E[i * NO + o] - lseE[i]);
}

// Main forward: one block of 1024 threads per batch. Thread = (i=tid>>1,
// h=tid&1), covering 256 k-values: 17 chunks VGPR + 9 LDS + 6 streamed.
// Half-pairs sit on adjacent lanes -> combine via shfl_xor(.,1).
__global__ __attribute__((amdgpu_flat_work_group_size(1024, 1024))) void k_fwd(
    const _Float16* __restrict__ Et, const int* __restrict__ x,
    const int* __restrict__ Tlen, const float* __restrict__ pi_sm,
    const uint4* __restrict__ Apk4, float* __restrict__ out) {
  __shared__ uint4 Alds[QLDS * 1024];  // 147456 B
  __shared__ uint4 vbuf4[2][NS / 8];   // 2 KB (fp16 v, chunk c at [h*32+c])
  __shared__ int xrow[TMAX];           // 2 KB
  __shared__ float red[16];
  int b = blockIdx.x, tid = threadIdx.x;
  int i = tid >> 1, h = tid & 1;

  // VGPR-resident A chunks (coalesced) + opaque pin against sinking/remat.
  uint4 areg[QREG];
#pragma unroll
  for (int q = 0; q < QREG; q++) areg[q] = Apk4[q * 1024 + tid];
#pragma unroll
  for (int q = 0; q < QREG; q++)
    asm volatile("" : "+v"(areg[q].x), "+v"(areg[q].y),
                      "+v"(areg[q].z), "+v"(areg[q].w));
#pragma unroll
  for (int q = 0; q < QLDS; q++)
    Alds[q * 1024 + tid] = Apk4[(QREG + q) * 1024 + tid];
  const uint4* Astr = Apk4 + (QREG + QLDS) * 1024 + tid;

  if (tid < TMAX) xrow[tid] = x[b * TMAX + tid];

  float pi_i = pi_sm[i];
  const _Float16* Etc = Et + i;
  int Tb = Tlen[b];
  float c = 0.f;
  int cur = 0;
  int vb = h << 5;   // v-chunk base for this half
  __syncthreads();

  for (int t = 0; t < Tb; t++) {
    int xt = xrow[t];
    _Float16 emh = Etc[(size_t)xt * NS];  // coalesced; hidden by dot phase
    float acc;
    if (t == 0) {
      acc = h ? 0.f : pi_i;
    } else {
      const uint4* vp = vbuf4[cur] + vb;
      uint4 sb[QSTR];
#pragma unroll
      for (int q = 0; q < QSTR; q++) sb[q] = Astr[q * 1024];
      float a0 = 0.f, a1 = 0.f, a2 = 0.f, a3 = 0.f;
#pragma unroll
      for (int q = 0; q < QREG; q++) {
        uint4 vv = vp[q];
        float* ch = (q & 3) == 0 ? &a0 : (q & 3) == 1 ? &a1 : (q & 3) == 2 ? &a2 : &a3;
        float t0 = dot2u(areg[q].x, vv.x, *ch);
        t0 = dot2u(areg[q].y, vv.y, t0);
        t0 = dot2u(areg[q].z, vv.z, t0);
        *ch = dot2u(areg[q].w, vv.w, t0);
      }
#pragma unroll
      for (int q = 0; q < QLDS; q++) {
        uint4 av = Alds[q * 1024 + tid];
        uint4 vv = vp[QREG + q];
        float* ch = (q & 3) == 0 ? &a0 : (q & 3) == 1 ? &a1 : (q & 3) == 2 ? &a2 : &a3;
        float t0 = dot2u(av.x, vv.x, *ch);
        t0 = dot2u(av.y, vv.y, t0);
        t0 = dot2u(av.z, vv.z, t0);
        *ch = dot2u(av.w, vv.w, t0);
      }
#pragma unroll
      for (int q = 0; q < QSTR; q++) {
        uint4 vv = vp[QREG + QLDS + q];
        float* ch = (q & 3) == 0 ? &a0 : (q & 3) == 1 ? &a1 : (q & 3) == 2 ? &a2 : &a3;
        float t0 = dot2u(sb[q].x, vv.x, *ch);
        t0 = dot2u(sb[q].y, vv.y, t0);
        t0 = dot2u(sb[q].z, vv.z, t0);
        *ch = dot2u(sb[q].w, vv.w, t0);
      }
      acc = (a0 + a1) + (a2 + a3);
    }
    // combine halves (adjacent lanes), emission multiply
    float acc_tot = acc + __shfl_xor(acc, 1, 64);
    float nv = acc_tot * (float)emh;          // both lanes of pair hold nv
    float s2 = wave_red_sum(nv);              // = 2 * partial sum
    if ((tid & 63) == 0) red[tid >> 6] = s2;
    __syncthreads();
    float4 r0 = *(const float4*)&red[0],  r1 = *(const float4*)&red[4];
    float4 r2 = *(const float4*)&red[8],  r3 = *(const float4*)&red[12];
    float s = 0.5f * (((r0.x + r0.y) + (r0.z + r0.w)) + ((r1.x + r1.y) + (r1.z + r1.w)) +
                      ((r2.x + r2.y) + (r2.z + r2.w)) + ((r3.x + r3.y) + (r3.z + r3.w)));
    float rs = __builtin_amdgcn_rcpf(s);
    c -= __logf(rs);                          // exact telescoping with rcp
    int nxt = cur ^ 1;
    if (h == 0) ((_Float16*)vbuf4[nxt])[i] = (_Float16)(nv * rs);
    __syncthreads();
    cur = nxt;
  }
  if (tid == 0) out[b] = c;
}

extern "C" void kernel_launch(void* const* d_in, const int* in_sizes, int n_in,
                              void* d_out, int out_size, void* d_ws, size_t ws_size,
                              hipStream_t stream) {
  const float* pi = (const float*)d_in[0];
  const float* A  = (const float*)d_in[1];
  const float* E  = (const float*)d_in[2];
  const int*   x  = (const int*)d_in[3];
  const int*   T  = (const int*)d_in[4];
  float* out = (float*)d_out;

  char* ws = (char*)d_ws;
  float*        pi_sm = (float*)(ws + 0);
  float*        lseA  = (float*)(ws + 2048);
  float*        lseE  = (float*)(ws + 4096);
  unsigned int* Apk   = (unsigned int*)(ws + 6144);            // 512 KB
  _Float16*     Et    = (_Float16*)(ws + 6144 + 524288);       // 1 MB

  hipLaunchKernelGGL(k_pi,      dim3(1),    dim3(512),  0, stream, pi, pi_sm);
  hipLaunchKernelGGL(k_colLse,  dim3(512),  dim3(256),  0, stream, A, lseA);
  hipLaunchKernelGGL(k_rowLseE, dim3(512),  dim3(256),  0, stream, E, lseE);
  hipLaunchKernelGGL(k_pack,    dim3(256),  dim3(512),  0, stream, A, lseA, Apk);
  hipLaunchKernelGGL(k_Et,      dim3(1024), dim3(512),  0, stream, E, lseE, Et);
  hipLaunchKernelGGL(k_fwd,     dim3(64),   dim3(1024), 0, stream,
                     Et, x, T, pi_sm, (const uint4*)Apk, out);
}